// Round 4
// baseline (35.091 us; speedup 1.0000x reference)
//
#include <hip/hip_runtime.h>
#include <hip/hip_bf16.h>
#include <cstddef>

typedef __attribute__((ext_vector_type(8))) short bf16x8;
typedef __attribute__((ext_vector_type(4))) float f32x4;
typedef __attribute__((ext_vector_type(2))) unsigned int u32x2;
typedef __attribute__((ext_vector_type(4))) unsigned int u32x4;

#define NB 4
#define CIN 64
#define COUT 64
#define HH 128
#define WW 128
#define TAPS 9
#define KCH 160      // padded K per chunk (144 real + 16 zero)
#define KTOT 640
#define STRD 84      // dwords per sCor row: 336 B, 16B-aligned, banks balanced

__device__ __forceinline__ float dpp_shr1(float v) {   // lane i <- lane i-1; lane0 <- 0
    int r = __builtin_amdgcn_update_dpp(0, __builtin_bit_cast(int, v), 0x138, 0xF, 0xF, true);
    return __builtin_bit_cast(float, r);
}
__device__ __forceinline__ float dpp_shl1(float v) {   // lane i <- lane i+1; lane63 <- 0
    int r = __builtin_amdgcn_update_dpp(0, __builtin_bit_cast(int, v), 0x130, 0xF, 0xF, true);
    return __builtin_bit_cast(float, r);
}

__device__ __forceinline__ unsigned short f2bf(float f) {
    union { float f; unsigned u; } v; v.f = f;
    unsigned u = v.u + 0x7FFFu + ((v.u >> 16) & 1u);   // RNE
    return (unsigned short)(u >> 16);
}

// wB[o][kk], kk = chunk*160 + tap*16 + cl (zero-pad kl 144..159); zrow = 192 zero floats
__global__ void prep_weight(const float* __restrict__ w, unsigned short* __restrict__ wB,
                            float* __restrict__ zrow) {
    int idx = blockIdx.x * blockDim.x + threadIdx.x;
    if (idx < 192) zrow[idx] = 0.f;
    if (idx >= COUT * KTOT) return;
    int o = idx / KTOT;
    int kk = idx - o * KTOT;
    int chunk = kk / KCH;
    int kl = kk - chunk * KCH;
    unsigned short v = 0;
    if (kl < 16 * TAPS) {
        int tap = kl >> 4;
        int cl = kl & 15;
        v = f2bf(w[(o * CIN + chunk * 16 + cl) * TAPS + tap]);
    }
    wB[idx] = v;
}

__launch_bounds__(512)
__global__ void pac_conv(const float* __restrict__ x, const float* __restrict__ Kp,
                         const unsigned short* __restrict__ wB,
                         const float* __restrict__ bias,
                         const float* __restrict__ zrow,
                         float* __restrict__ out) {
    __shared__ __align__(16) unsigned int sCor[128][STRD];   // 43008 B

    const int blk0 = blockIdx.x;                       // 512
    const int blk  = ((blk0 & 7) << 6) | (blk0 >> 3);  // XCD-chunked swizzle (bijective, 512%8==0)
    const int h = blk & (HH - 1);
    const int n = blk >> 7;

    const int t = threadIdx.x;
    const int lane = t & 63;
    const int w = __builtin_amdgcn_readfirstlane(t >> 6);  // 0..7
    const int q = w & 3;              // output-channel quad & staging channel quad
    const int half = w >> 2;          // px half
    const int px = half * 64 + lane;  // this thread's pixel

    // adapting kernel for this pixel -> registers
    const float* kp = Kp + (size_t)n * TAPS * HH * WW + (size_t)h * WW + px;
    float kreg[TAPS];
    float ks = 0.f;
    #pragma unroll
    for (int tap = 0; tap < TAPS; ++tap) {
        kreg[tap] = kp[(size_t)tap * HH * WW];
        ks += kreg[tap];
    }
    const float inv = 1.0f / ks;

    // zero K-pad dwords 72..79 of every row (once)
    for (int i = t; i < 128 * 8; i += 512) sCor[i >> 3][72 + (i & 7)] = 0u;

    // mid-seam halo: half0 lane63 needs px64; half1 lane0 needs px63
    const bool hneed = (half == 0) ? (lane == 63) : (lane == 0);
    const int  hoff  = (half == 0) ? 64 : 63;

    const int l15 = lane & 15;
    const int g   = lane >> 4;

    f32x4 acc[4];
    #pragma unroll
    for (int i = 0; i < 4; ++i) acc[i] = (f32x4){0.f, 0.f, 0.f, 0.f};

    for (int chunk = 0; chunk < 4; ++chunk) {
        u32x2 cor[TAPS];
        float prev[TAPS];
        #pragma unroll
        for (int j = 0; j < 4; ++j) {
            const int c = chunk * 16 + q * 4 + j;
            const float* xrow0 = x + ((size_t)(n * CIN + c) * HH) * WW;
            float xv[TAPS];
            #pragma unroll
            for (int k = 0; k < 3; ++k) {
                const int hh = h + k - 1;
                const float* rp = ((unsigned)hh < (unsigned)HH) ? (xrow0 + (size_t)hh * WW) : zrow;
                const float vC = rp[px];
                float hv = 0.f;
                if (hneed) hv = rp[hoff];
                float vL = dpp_shr1(vC);
                float vR = dpp_shl1(vC);
                if (half == 0) { if (lane == 63) vR = hv; }   // px63 right = px64
                else           { if (lane == 0)  vL = hv; }   // px64 left  = px63
                xv[k * 3 + 0] = vL;
                xv[k * 3 + 1] = vC;
                xv[k * 3 + 2] = vR;
            }
            float s = 0.f;
            #pragma unroll
            for (int tap = 0; tap < TAPS; ++tap) s = fmaf(xv[tap], kreg[tap], s);
            const float d = s * inv;
            if (j & 1) {
                #pragma unroll
                for (int tap = 0; tap < TAPS; ++tap) {
                    float cc = fmaf(kreg[tap], xv[tap] - d, d);
                    union { __hip_bfloat162 h2; unsigned int u; } pk;
                    pk.h2 = __float22bfloat162_rn(make_float2(prev[tap], cc));
                    cor[tap][j >> 1] = pk.u;
                }
            } else {
                #pragma unroll
                for (int tap = 0; tap < TAPS; ++tap)
                    prev[tap] = fmaf(kreg[tap], xv[tap] - d, d);
            }
        }

        if (chunk) __syncthreads();            // previous MFMA readers done
        #pragma unroll
        for (int tap = 0; tap < TAPS; ++tap)
            *reinterpret_cast<u32x2*>(&sCor[px][tap * 8 + q * 2]) = cor[tap];
        __syncthreads();

        // MFMA: wave (q,half) -> outputs q*16..+15, pixels half*64..+63
        const unsigned short* wrow = wB + (size_t)(q * 16 + l15) * KTOT + chunk * KCH + g * 8;
        #pragma unroll
        for (int step = 0; step < 5; ++step) {
            bf16x8 bfrag = *reinterpret_cast<const bf16x8*>(wrow + step * 32);
            #pragma unroll
            for (int pt = 0; pt < 4; ++pt) {
                const int row = half * 64 + pt * 16 + l15;
                u32x4 a = *reinterpret_cast<const u32x4*>(&sCor[row][step * 16 + g * 4]);
                acc[pt] = __builtin_amdgcn_mfma_f32_16x16x32_bf16(
                    __builtin_bit_cast(bf16x8, a), bfrag, acc[pt], 0, 0, 0);
            }
        }
    }

    // epilogue: direct float4 stores (D: col=o=l15, rows = g*4+r within 16-tile)
    const int o = q * 16 + l15;
    const float bval = bias[o];
    float* op = out + (((size_t)n * COUT + o) * HH + h) * WW + half * 64 + g * 4;
    #pragma unroll
    for (int pt = 0; pt < 4; ++pt) {
        f32x4 v = acc[pt];
        #pragma unroll
        for (int r = 0; r < 4; ++r) v[r] += bval;
        *reinterpret_cast<f32x4*>(op + pt * 16) = v;
    }
}

extern "C" void kernel_launch(void* const* d_in, const int* in_sizes, int n_in,
                              void* d_out, int out_size, void* d_ws, size_t ws_size,
                              hipStream_t stream) {
    const float* x    = (const float*)d_in[0];
    const float* Kp   = (const float*)d_in[1];
    const float* wgt  = (const float*)d_in[2];
    const float* bias = (const float*)d_in[3];
    float* out = (float*)d_out;
    unsigned short* wB = (unsigned short*)d_ws;        // 81920 B
    float* zrow = (float*)((char*)d_ws + 81920);       // 192 zero floats

    prep_weight<<<(COUT * KTOT + 255) / 256, 256, 0, stream>>>(wgt, wB, zrow);

    pac_conv<<<NB * HH, 512, 0, stream>>>(x, Kp, wB, bias, zrow, out);
}